// Round 1
// baseline (424.513 us; speedup 1.0000x reference)
//
#include <hip/hip_runtime.h>

// GCN 2-layer: N=50000 nodes, E=800000 edges, 128 -> 128(relu) -> 64
// Strategy: build CSR-by-dst once (histogram + scan + fill), pre-scale
// h' = dinv[i] * (x@W) in GEMM epilogue, wave-per-node gather-aggregate
// (no atomics in the hot path), final scale by dinv[dst] + bias (+relu).

#define N_NODES 50000
#define N_EDGES 800000

// ---------------- CSR build ----------------

__global__ void count_kernel(const int* __restrict__ dst, int* __restrict__ deg) {
    int e = blockIdx.x * 256 + threadIdx.x;
    if (e < N_EDGES) atomicAdd(&deg[dst[e]], 1);
}

// chunk = 1024 elements per block (49 blocks cover 50000)
__global__ void scan_part_kernel(const int* __restrict__ deg, int* __restrict__ partials) {
    __shared__ int red[256];
    int tid = threadIdx.x;
    int base = blockIdx.x * 1024 + tid * 4;
    int s = 0;
#pragma unroll
    for (int i = 0; i < 4; i++) { int idx = base + i; if (idx < N_NODES) s += deg[idx]; }
    red[tid] = s; __syncthreads();
    for (int off = 128; off > 0; off >>= 1) {
        if (tid < off) red[tid] += red[tid + off];
        __syncthreads();
    }
    if (tid == 0) partials[blockIdx.x] = red[0];
}

__global__ void scan_blocks_kernel(int* partials, int nb) {
    if (threadIdx.x == 0 && blockIdx.x == 0) {
        int run = 0;
        for (int i = 0; i < nb; i++) { int v = partials[i]; partials[i] = run; run += v; }
    }
}

__global__ void scan_final_kernel(const int* __restrict__ deg, const int* __restrict__ poff,
                                  int* __restrict__ row_off, int* __restrict__ cursor,
                                  float* __restrict__ dinv) {
    __shared__ int sc[256];
    int tid = threadIdx.x;
    int base = blockIdx.x * 1024 + tid * 4;
    int v[4]; int s = 0;
#pragma unroll
    for (int i = 0; i < 4; i++) { int idx = base + i; v[i] = (idx < N_NODES) ? deg[idx] : 0; s += v[i]; }
    sc[tid] = s; __syncthreads();
    // Hillis-Steele inclusive scan over 256 thread sums
    for (int off = 1; off < 256; off <<= 1) {
        int t = (tid >= off) ? sc[tid - off] : 0;
        __syncthreads();
        sc[tid] += t;
        __syncthreads();
    }
    int run = sc[tid] - s + poff[blockIdx.x];   // exclusive prefix for this thread
#pragma unroll
    for (int i = 0; i < 4; i++) {
        int idx = base + i;
        if (idx < N_NODES) {
            row_off[idx] = run;
            cursor[idx]  = run;
            dinv[idx]    = rsqrtf((float)(v[i] + 1));   // +1 self-loop, always > 0
            run += v[i];
        }
    }
}

__global__ void fill_kernel(const int* __restrict__ src, const int* __restrict__ dst,
                            int* __restrict__ cursor, int* __restrict__ ssrc) {
    int e = blockIdx.x * 256 + threadIdx.x;
    if (e < N_EDGES) {
        int d = dst[e];
        int p = atomicAdd(&cursor[d], 1);
        ssrc[p] = src[e];
    }
}

// ---------------- GEMM: H[i] = dinv[i] * (X @ W)[i], K = 128 ----------------
// block tile 64 rows x 64 cols, 256 threads, 4x4 register tile, K chunked by 64.
template<int OUTC>
__global__ __launch_bounds__(256) void gemm_scale_kernel(
        const float* __restrict__ X, const float* __restrict__ W,
        const float* __restrict__ dinv, float* __restrict__ H) {
    __shared__ float Ws[128][64];   // 32 KB, full K
    __shared__ float Xs[64][68];    // 17 KB per 64-K chunk; stride 68 -> 16B-aligned rows, 2-way banks
    int tid = threadIdx.x;
    int rb = blockIdx.x * 64;
    int cb = blockIdx.y * 64;

    for (int i = tid; i < 128 * 64; i += 256) {
        int k = i >> 6, c = i & 63;
        Ws[k][c] = W[k * OUTC + cb + c];
    }

    int tx = tid & 15, ty = tid >> 4;
    int r0 = ty * 4, c0 = tx * 4;
    float acc[4][4] = {};

    for (int kb = 0; kb < 128; kb += 64) {
        __syncthreads();   // also covers Ws readiness on first iter
        for (int i = tid; i < 64 * 64; i += 256) {
            int r = i >> 6, kk = i & 63;
            int gr = rb + r;
            Xs[r][kk] = (gr < N_NODES) ? X[gr * 128 + kb + kk] : 0.f;
        }
        __syncthreads();
        for (int kk = 0; kk < 64; kk += 4) {
            float4 xv[4], wv[4];
#pragma unroll
            for (int i = 0; i < 4; i++) xv[i] = *(const float4*)&Xs[r0 + i][kk];
#pragma unroll
            for (int j = 0; j < 4; j++) wv[j] = *(const float4*)&Ws[kb + kk + j][c0];
#pragma unroll
            for (int j = 0; j < 4; j++) {
#pragma unroll
                for (int i = 0; i < 4; i++) {
                    float xx = ((const float*)&xv[i])[j];
                    acc[i][0] = fmaf(xx, wv[j].x, acc[i][0]);
                    acc[i][1] = fmaf(xx, wv[j].y, acc[i][1]);
                    acc[i][2] = fmaf(xx, wv[j].z, acc[i][2]);
                    acc[i][3] = fmaf(xx, wv[j].w, acc[i][3]);
                }
            }
        }
    }

#pragma unroll
    for (int i = 0; i < 4; i++) {
        int gr = rb + r0 + i;
        if (gr < N_NODES) {
            float s = dinv[gr];
            float4 o = make_float4(acc[i][0] * s, acc[i][1] * s, acc[i][2] * s, acc[i][3] * s);
            *(float4*)&H[gr * OUTC + cb + c0] = o;
        }
    }
}

// ---------------- Aggregate: out[i] = act(dinv[i]*(H[i] + sum_{e:dst=i} H[src]) + b) --------
// one 64-lane wave per node; CH=128 -> float2 per lane, CH=64 -> float per lane.
template<int CH, bool RELU>
__global__ __launch_bounds__(256) void aggregate_kernel(
        const float* __restrict__ H, const int* __restrict__ row_off,
        const int* __restrict__ deg, const int* __restrict__ ssrc,
        const float* __restrict__ dinv, const float* __restrict__ bias,
        float* __restrict__ out) {
    int node = (blockIdx.x * 256 + threadIdx.x) >> 6;
    int lane = threadIdx.x & 63;
    if (node >= N_NODES) return;
    int beg = row_off[node];
    int d   = deg[node];
    float di = dinv[node];
    if constexpr (CH == 128) {
        const float2* Hv = (const float2*)H;
        float2 acc = Hv[node * 64 + lane];          // self-loop term
        for (int j = 0; j < d; j++) {
            int s = ssrc[beg + j];
            float2 v = Hv[s * 64 + lane];
            acc.x += v.x; acc.y += v.y;
        }
        float2 b = ((const float2*)bias)[lane];
        float2 o = make_float2(fmaf(di, acc.x, b.x), fmaf(di, acc.y, b.y));
        if (RELU) { o.x = fmaxf(o.x, 0.f); o.y = fmaxf(o.y, 0.f); }
        ((float2*)out)[node * 64 + lane] = o;
    } else {
        float acc = H[node * 64 + lane];            // self-loop term
        for (int j = 0; j < d; j++) {
            int s = ssrc[beg + j];
            acc += H[s * 64 + lane];
        }
        float o = fmaf(di, acc, bias[lane]);
        if (RELU) o = fmaxf(o, 0.f);
        out[node * 64 + lane] = o;
    }
}

// ---------------- launch ----------------

extern "C" void kernel_launch(void* const* d_in, const int* in_sizes, int n_in,
                              void* d_out, int out_size, void* d_ws, size_t ws_size,
                              hipStream_t stream) {
    const float* x  = (const float*)d_in[0];   // [N,128]
    const int*   ei = (const int*)d_in[1];     // [2,E]
    const float* W1 = (const float*)d_in[2];   // [128,128]
    const float* b1 = (const float*)d_in[3];   // [128]
    const float* W2 = (const float*)d_in[4];   // [128,64]
    const float* b2 = (const float*)d_in[5];   // [64]
    float* out = (float*)d_out;                // [N,64]

    const int* src = ei;
    const int* dst = ei + N_EDGES;

    // workspace carve-up (~52.7 MiB total)
    char* p = (char*)d_ws;
    size_t off = 0;
    auto alloc = [&](size_t bytes) { void* q = p + off; off += (bytes + 255) & ~(size_t)255; return q; };
    float* dinv    = (float*)alloc(N_NODES * 4);
    int*   deg     = (int*)  alloc(N_NODES * 4);
    int*   row_off = (int*)  alloc(N_NODES * 4);
    int*   cursor  = (int*)  alloc(N_NODES * 4);
    int*   parts   = (int*)  alloc(64 * 4);            // 49 used
    int*   ssrc    = (int*)  alloc(N_EDGES * 4);
    float* h_buf   = (float*)alloc((size_t)N_NODES * 128 * 4);
    float* x2      = (float*)alloc((size_t)N_NODES * 128 * 4);

    const int nb_scan = (N_NODES + 1023) / 1024;       // 49

    hipMemsetAsync(deg, 0, N_NODES * sizeof(int), stream);
    count_kernel<<<(N_EDGES + 255) / 256, 256, 0, stream>>>(dst, deg);
    scan_part_kernel<<<nb_scan, 256, 0, stream>>>(deg, parts);
    scan_blocks_kernel<<<1, 64, 0, stream>>>(parts, nb_scan);
    scan_final_kernel<<<nb_scan, 256, 0, stream>>>(deg, parts, row_off, cursor, dinv);
    fill_kernel<<<(N_EDGES + 255) / 256, 256, 0, stream>>>(src, dst, cursor, ssrc);

    // layer 1: h' = dinv * (x @ W1); x2 = relu(dinv * (h'[self] + sum h'[src]) + b1)
    gemm_scale_kernel<128><<<dim3((N_NODES + 63) / 64, 2), 256, 0, stream>>>(x, W1, dinv, h_buf);
    aggregate_kernel<128, true><<<(N_NODES * 64 + 255) / 256, 256, 0, stream>>>(
        h_buf, row_off, deg, ssrc, dinv, b1, x2);

    // layer 2: h2' = dinv * (x2 @ W2); out = dinv * (h2'[self] + sum h2'[src]) + b2
    gemm_scale_kernel<64><<<dim3((N_NODES + 63) / 64, 1), 256, 0, stream>>>(x2, W2, dinv, h_buf);
    aggregate_kernel<64, false><<<(N_NODES * 64 + 255) / 256, 256, 0, stream>>>(
        h_buf, row_off, deg, ssrc, dinv, b2, out);
}

// Round 2
// 344.776 us; speedup vs baseline: 1.2313x; 1.2313x over previous
//
#include <hip/hip_runtime.h>

// GCN 2-layer: N=50000 nodes, E=800000 edges, 128 -> 128(relu) -> 64
// CSR-by-dst build -> pre-scaled h' = dinv*(x@W) -> wave-per-node gather
// aggregate with 8-wide batched loads (MLP), final dinv*sum + bias (+relu).

#define N_NODES 50000
#define N_EDGES 800000

// ---------------- CSR build ----------------

__global__ void count_kernel(const int* __restrict__ dst, int* __restrict__ deg) {
    int e = blockIdx.x * 256 + threadIdx.x;
    if (e < N_EDGES) atomicAdd(&deg[dst[e]], 1);
}

// chunk = 1024 elements per block (49 blocks cover 50000)
__global__ void scan_part_kernel(const int* __restrict__ deg, int* __restrict__ partials) {
    __shared__ int red[256];
    int tid = threadIdx.x;
    int base = blockIdx.x * 1024 + tid * 4;
    int s = 0;
#pragma unroll
    for (int i = 0; i < 4; i++) { int idx = base + i; if (idx < N_NODES) s += deg[idx]; }
    red[tid] = s; __syncthreads();
    for (int off = 128; off > 0; off >>= 1) {
        if (tid < off) red[tid] += red[tid + off];
        __syncthreads();
    }
    if (tid == 0) partials[blockIdx.x] = red[0];
}

// wave-parallel exclusive scan over <=64 block partials
__global__ void scan_blocks_kernel(int* partials, int nb) {
    int tid = threadIdx.x;            // 64 threads, one wave
    int orig = (tid < nb) ? partials[tid] : 0;
    int v = orig;
    for (int off = 1; off < 64; off <<= 1) {
        int t = __shfl_up(v, off, 64);
        if (tid >= off) v += t;
    }
    if (tid < nb) partials[tid] = v - orig;   // exclusive
}

__global__ void scan_final_kernel(const int* __restrict__ deg, const int* __restrict__ poff,
                                  int* __restrict__ row_off, int* __restrict__ cursor,
                                  float* __restrict__ dinv) {
    __shared__ int sc[256];
    int tid = threadIdx.x;
    int base = blockIdx.x * 1024 + tid * 4;
    int v[4]; int s = 0;
#pragma unroll
    for (int i = 0; i < 4; i++) { int idx = base + i; v[i] = (idx < N_NODES) ? deg[idx] : 0; s += v[i]; }
    sc[tid] = s; __syncthreads();
    for (int off = 1; off < 256; off <<= 1) {
        int t = (tid >= off) ? sc[tid - off] : 0;
        __syncthreads();
        sc[tid] += t;
        __syncthreads();
    }
    int run = sc[tid] - s + poff[blockIdx.x];   // exclusive prefix for this thread
#pragma unroll
    for (int i = 0; i < 4; i++) {
        int idx = base + i;
        if (idx < N_NODES) {
            row_off[idx] = run;
            cursor[idx]  = run;
            dinv[idx]    = rsqrtf((float)(v[i] + 1));   // +1 self-loop, always > 0
            run += v[i];
        }
    }
}

__global__ void fill_kernel(const int* __restrict__ src, const int* __restrict__ dst,
                            int* __restrict__ cursor, int* __restrict__ ssrc) {
    int e = blockIdx.x * 256 + threadIdx.x;
    if (e < N_EDGES) {
        int d = dst[e];
        int p = atomicAdd(&cursor[d], 1);
        ssrc[p] = src[e];
    }
}

// ---------------- GEMM: H[i] = dinv[i] * (X @ W)[i], K = 128 ----------------
template<int OUTC>
__global__ __launch_bounds__(256) void gemm_scale_kernel(
        const float* __restrict__ X, const float* __restrict__ W,
        const float* __restrict__ dinv, float* __restrict__ H) {
    __shared__ float Ws[128][64];   // 32 KB, full K
    __shared__ float Xs[64][68];    // 17 KB per 64-K chunk
    int tid = threadIdx.x;
    int rb = blockIdx.x * 64;
    int cb = blockIdx.y * 64;

    for (int i = tid; i < 128 * 64; i += 256) {
        int k = i >> 6, c = i & 63;
        Ws[k][c] = W[k * OUTC + cb + c];
    }

    int tx = tid & 15, ty = tid >> 4;
    int r0 = ty * 4, c0 = tx * 4;
    float acc[4][4] = {};

    for (int kb = 0; kb < 128; kb += 64) {
        __syncthreads();
        for (int i = tid; i < 64 * 64; i += 256) {
            int r = i >> 6, kk = i & 63;
            int gr = rb + r;
            Xs[r][kk] = (gr < N_NODES) ? X[gr * 128 + kb + kk] : 0.f;
        }
        __syncthreads();
        for (int kk = 0; kk < 64; kk += 4) {
            float4 xv[4], wv[4];
#pragma unroll
            for (int i = 0; i < 4; i++) xv[i] = *(const float4*)&Xs[r0 + i][kk];
#pragma unroll
            for (int j = 0; j < 4; j++) wv[j] = *(const float4*)&Ws[kb + kk + j][c0];
#pragma unroll
            for (int j = 0; j < 4; j++) {
#pragma unroll
                for (int i = 0; i < 4; i++) {
                    float xx = ((const float*)&xv[i])[j];
                    acc[i][0] = fmaf(xx, wv[j].x, acc[i][0]);
                    acc[i][1] = fmaf(xx, wv[j].y, acc[i][1]);
                    acc[i][2] = fmaf(xx, wv[j].z, acc[i][2]);
                    acc[i][3] = fmaf(xx, wv[j].w, acc[i][3]);
                }
            }
        }
    }

#pragma unroll
    for (int i = 0; i < 4; i++) {
        int gr = rb + r0 + i;
        if (gr < N_NODES) {
            float s = dinv[gr];
            float4 o = make_float4(acc[i][0] * s, acc[i][1] * s, acc[i][2] * s, acc[i][3] * s);
            *(float4*)&H[gr * OUTC + cb + c0] = o;
        }
    }
}

// ---------------- Aggregate: out[i] = act(dinv[i]*(H[i] + sum_{e:dst=i} H[src]) + b) --------
// one 64-lane wave per node; batched 8-wide edge loads for memory-level parallelism.
// d/beg/di are wave-uniform -> no divergence; tail batches pad with a duplicate
// valid index (L1 hit) and predicate the accumulate.
template<int CH, bool RELU>
__global__ __launch_bounds__(256) void aggregate_kernel(
        const float* __restrict__ H, const int* __restrict__ row_off,
        const int* __restrict__ deg, const int* __restrict__ ssrc,
        const float* __restrict__ dinv, const float* __restrict__ bias,
        float* __restrict__ out) {
    int node = (blockIdx.x * 256 + threadIdx.x) >> 6;
    int lane = threadIdx.x & 63;
    if (node >= N_NODES) return;
    int beg = row_off[node];
    int d   = deg[node];
    float di = dinv[node];
    if constexpr (CH == 128) {
        const float2* Hv = (const float2*)H;
        float2 acc = Hv[(size_t)node * 64 + lane];          // self-loop term
        for (int j = 0; j < d; j += 8) {
            int s[8]; float2 v[8];
#pragma unroll
            for (int u = 0; u < 8; u++) {
                int idx = j + u;
                s[u] = ssrc[beg + ((idx < d) ? idx : (d - 1))];
            }
#pragma unroll
            for (int u = 0; u < 8; u++) v[u] = Hv[(size_t)s[u] * 64 + lane];
#pragma unroll
            for (int u = 0; u < 8; u++) {
                if (j + u < d) { acc.x += v[u].x; acc.y += v[u].y; }
            }
        }
        float2 b = ((const float2*)bias)[lane];
        float2 o = make_float2(fmaf(di, acc.x, b.x), fmaf(di, acc.y, b.y));
        if (RELU) { o.x = fmaxf(o.x, 0.f); o.y = fmaxf(o.y, 0.f); }
        ((float2*)out)[(size_t)node * 64 + lane] = o;
    } else {
        float acc = H[(size_t)node * 64 + lane];            // self-loop term
        for (int j = 0; j < d; j += 8) {
            int s[8]; float v[8];
#pragma unroll
            for (int u = 0; u < 8; u++) {
                int idx = j + u;
                s[u] = ssrc[beg + ((idx < d) ? idx : (d - 1))];
            }
#pragma unroll
            for (int u = 0; u < 8; u++) v[u] = H[(size_t)s[u] * 64 + lane];
#pragma unroll
            for (int u = 0; u < 8; u++) {
                if (j + u < d) acc += v[u];
            }
        }
        float o = fmaf(di, acc, bias[lane]);
        if (RELU) o = fmaxf(o, 0.f);
        out[(size_t)node * 64 + lane] = o;
    }
}

// ---------------- launch ----------------

extern "C" void kernel_launch(void* const* d_in, const int* in_sizes, int n_in,
                              void* d_out, int out_size, void* d_ws, size_t ws_size,
                              hipStream_t stream) {
    const float* x  = (const float*)d_in[0];   // [N,128]
    const int*   ei = (const int*)d_in[1];     // [2,E]
    const float* W1 = (const float*)d_in[2];   // [128,128]
    const float* b1 = (const float*)d_in[3];   // [128]
    const float* W2 = (const float*)d_in[4];   // [128,64]
    const float* b2 = (const float*)d_in[5];   // [64]
    float* out = (float*)d_out;                // [N,64]

    const int* src = ei;
    const int* dst = ei + N_EDGES;

    char* p = (char*)d_ws;
    size_t off = 0;
    auto alloc = [&](size_t bytes) { void* q = p + off; off += (bytes + 255) & ~(size_t)255; return q; };
    float* dinv    = (float*)alloc(N_NODES * 4);
    int*   deg     = (int*)  alloc(N_NODES * 4);
    int*   row_off = (int*)  alloc(N_NODES * 4);
    int*   cursor  = (int*)  alloc(N_NODES * 4);
    int*   parts   = (int*)  alloc(64 * 4);            // 49 used
    int*   ssrc    = (int*)  alloc(N_EDGES * 4);
    float* h_buf   = (float*)alloc((size_t)N_NODES * 128 * 4);
    float* x2      = (float*)alloc((size_t)N_NODES * 128 * 4);

    const int nb_scan = (N_NODES + 1023) / 1024;       // 49

    hipMemsetAsync(deg, 0, N_NODES * sizeof(int), stream);
    count_kernel<<<(N_EDGES + 255) / 256, 256, 0, stream>>>(dst, deg);
    scan_part_kernel<<<nb_scan, 256, 0, stream>>>(deg, parts);
    scan_blocks_kernel<<<1, 64, 0, stream>>>(parts, nb_scan);
    scan_final_kernel<<<nb_scan, 256, 0, stream>>>(deg, parts, row_off, cursor, dinv);
    fill_kernel<<<(N_EDGES + 255) / 256, 256, 0, stream>>>(src, dst, cursor, ssrc);

    // layer 1
    gemm_scale_kernel<128><<<dim3((N_NODES + 63) / 64, 2), 256, 0, stream>>>(x, W1, dinv, h_buf);
    aggregate_kernel<128, true><<<(N_NODES * 64 + 255) / 256, 256, 0, stream>>>(
        h_buf, row_off, deg, ssrc, dinv, b1, x2);

    // layer 2
    gemm_scale_kernel<64><<<dim3((N_NODES + 63) / 64, 1), 256, 0, stream>>>(x2, W2, dinv, h_buf);
    aggregate_kernel<64, false><<<(N_NODES * 64 + 255) / 256, 256, 0, stream>>>(
        h_buf, row_off, deg, ssrc, dinv, b2, out);
}

// Round 3
// 291.714 us; speedup vs baseline: 1.4552x; 1.1819x over previous
//
#include <hip/hip_runtime.h>

// GCN 2-layer: N=50000 nodes, E=800000 edges, 128 -> 128(relu) -> 64
// CSR-by-dst build -> h' = dinv*(x@W) via bf16 MFMA with 3-term hi/lo split
// (f32-quality) -> wave-per-node gather aggregate (8-wide MLP batching).

#define N_NODES 50000
#define N_EDGES 800000

typedef __bf16 bf16x8 __attribute__((ext_vector_type(8)));
typedef float  f32x4  __attribute__((ext_vector_type(4)));

// ---------------- CSR build ----------------

__global__ void count_kernel(const int* __restrict__ dst, int* __restrict__ deg) {
    int e = blockIdx.x * 256 + threadIdx.x;
    if (e < N_EDGES) atomicAdd(&deg[dst[e]], 1);
}

__global__ void scan_part_kernel(const int* __restrict__ deg, int* __restrict__ partials) {
    __shared__ int red[256];
    int tid = threadIdx.x;
    int base = blockIdx.x * 1024 + tid * 4;
    int s = 0;
#pragma unroll
    for (int i = 0; i < 4; i++) { int idx = base + i; if (idx < N_NODES) s += deg[idx]; }
    red[tid] = s; __syncthreads();
    for (int off = 128; off > 0; off >>= 1) {
        if (tid < off) red[tid] += red[tid + off];
        __syncthreads();
    }
    if (tid == 0) partials[blockIdx.x] = red[0];
}

__global__ void scan_blocks_kernel(int* partials, int nb) {
    int tid = threadIdx.x;            // 64 threads, one wave
    int orig = (tid < nb) ? partials[tid] : 0;
    int v = orig;
    for (int off = 1; off < 64; off <<= 1) {
        int t = __shfl_up(v, off, 64);
        if (tid >= off) v += t;
    }
    if (tid < nb) partials[tid] = v - orig;   // exclusive
}

__global__ void scan_final_kernel(const int* __restrict__ deg, const int* __restrict__ poff,
                                  int* __restrict__ row_off, int* __restrict__ cursor,
                                  float* __restrict__ dinv) {
    __shared__ int sc[256];
    int tid = threadIdx.x;
    int base = blockIdx.x * 1024 + tid * 4;
    int v[4]; int s = 0;
#pragma unroll
    for (int i = 0; i < 4; i++) { int idx = base + i; v[i] = (idx < N_NODES) ? deg[idx] : 0; s += v[i]; }
    sc[tid] = s; __syncthreads();
    for (int off = 1; off < 256; off <<= 1) {
        int t = (tid >= off) ? sc[tid - off] : 0;
        __syncthreads();
        sc[tid] += t;
        __syncthreads();
    }
    int run = sc[tid] - s + poff[blockIdx.x];
#pragma unroll
    for (int i = 0; i < 4; i++) {
        int idx = base + i;
        if (idx < N_NODES) {
            row_off[idx] = run;
            cursor[idx]  = run;
            dinv[idx]    = rsqrtf((float)(v[i] + 1));   // +1 self-loop
            run += v[i];
        }
    }
}

__global__ void fill_kernel(const int* __restrict__ src, const int* __restrict__ dst,
                            int* __restrict__ cursor, int* __restrict__ ssrc) {
    int e = blockIdx.x * 256 + threadIdx.x;
    if (e < N_EDGES) {
        int d = dst[e];
        int p = atomicAdd(&cursor[d], 1);
        ssrc[p] = src[e];
    }
}

// ---------------- W prep: f32 [K=128][N] -> hi/lo bf16 B-fragments ----------------
// B-operand layout for mfma_f32_16x16x32_bf16: lane l holds B[k0+(l>>4)*8+j][n0+(l&15)],
// j=0..7. Swizzled storage: frag[(c*4+s)*64 + l][j], 16B contiguous per lane.
template<int N>
__global__ void wprep_kernel(const float* __restrict__ W,
                             __bf16* __restrict__ hi, __bf16* __restrict__ lo) {
    int idx = blockIdx.x * 256 + threadIdx.x;     // total (N/16)*4*64 = N*16
    if (idx >= (N / 16) * 4 * 64) return;
    int l = idx & 63;
    int s = (idx >> 6) & 3;
    int c = idx >> 8;
    int n = c * 16 + (l & 15);
    int k0 = s * 32 + (l >> 4) * 8;
#pragma unroll
    for (int j = 0; j < 8; j++) {
        float w = W[(k0 + j) * N + n];
        __bf16 h = (__bf16)w;
        hi[idx * 8 + j] = h;
        lo[idx * 8 + j] = (__bf16)(w - (float)h);
    }
}

// ---------------- GEMM: H = dinv * (X @ W) via split-bf16 MFMA ----------------
// block = 256 thr = 4 waves; wave w does rows [rb+16w, rb+16w+16) x all OUTC cols.
// A-frag: lane l holds X[row = rb+16w+(l&15)][k0+(l>>4)*8+j] (8 consecutive f32,
// split into hi/lo bf16). 3 MFMAs per (c,s): ah*bh + al*bh + ah*bl.
template<int OUTC>
__global__ __launch_bounds__(256) void gemm_mfma_kernel(
        const float* __restrict__ X, const __bf16* __restrict__ Whi,
        const __bf16* __restrict__ Wlo, const float* __restrict__ dinv,
        float* __restrict__ H) {
    constexpr int NC = OUTC / 16;
    int tid = threadIdx.x;
    int w = tid >> 6, lane = tid & 63;
    int q = lane >> 4, lr = lane & 15;
    int rb = blockIdx.x * 64 + w * 16;
    int row = rb + lr;
    int rowc = (row < N_NODES) ? row : (N_NODES - 1);

    f32x4 acc[NC];
#pragma unroll
    for (int c = 0; c < NC; c++) acc[c] = (f32x4){0.f, 0.f, 0.f, 0.f};

#pragma unroll
    for (int s = 0; s < 4; s++) {
        const float* xp = X + (size_t)rowc * 128 + s * 32 + q * 8;
        float4 x0 = *(const float4*)xp;
        float4 x1 = *(const float4*)(xp + 4);
        float xv[8] = {x0.x, x0.y, x0.z, x0.w, x1.x, x1.y, x1.z, x1.w};
        bf16x8 a_hi, a_lo;
#pragma unroll
        for (int j = 0; j < 8; j++) {
            __bf16 h = (__bf16)xv[j];
            a_hi[j] = h;
            a_lo[j] = (__bf16)(xv[j] - (float)h);
        }
#pragma unroll
        for (int c = 0; c < NC; c++) {
            size_t fo = (size_t)((c * 4 + s) * 64 + lane) * 8;
            bf16x8 bh = *(const bf16x8*)(Whi + fo);
            bf16x8 bl = *(const bf16x8*)(Wlo + fo);
            acc[c] = __builtin_amdgcn_mfma_f32_16x16x32_bf16(a_hi, bh, acc[c], 0, 0, 0);
            acc[c] = __builtin_amdgcn_mfma_f32_16x16x32_bf16(a_lo, bh, acc[c], 0, 0, 0);
            acc[c] = __builtin_amdgcn_mfma_f32_16x16x32_bf16(a_hi, bl, acc[c], 0, 0, 0);
        }
    }

    // C/D layout: col = c*16 + (lane&15), row(within 16) = (lane>>4)*4 + reg
#pragma unroll
    for (int r = 0; r < 4; r++) {
        int grow = rb + q * 4 + r;
        if (grow < N_NODES) {
            float sc = dinv[grow];
#pragma unroll
            for (int c = 0; c < NC; c++) {
                H[(size_t)grow * OUTC + c * 16 + lr] = acc[c][r] * sc;
            }
        }
    }
}

// ---------------- Aggregate: out[i] = act(dinv[i]*(H[i] + sum_{e:dst=i} H[src]) + b) --------
template<int CH, bool RELU>
__global__ __launch_bounds__(256) void aggregate_kernel(
        const float* __restrict__ H, const int* __restrict__ row_off,
        const int* __restrict__ deg, const int* __restrict__ ssrc,
        const float* __restrict__ dinv, const float* __restrict__ bias,
        float* __restrict__ out) {
    int node = (blockIdx.x * 256 + threadIdx.x) >> 6;
    int lane = threadIdx.x & 63;
    if (node >= N_NODES) return;
    int beg = row_off[node];
    int d   = deg[node];
    float di = dinv[node];
    if constexpr (CH == 128) {
        const float2* Hv = (const float2*)H;
        float2 acc = Hv[(size_t)node * 64 + lane];          // self-loop term
        for (int j = 0; j < d; j += 8) {
            int s[8]; float2 v[8];
#pragma unroll
            for (int u = 0; u < 8; u++) {
                int idx = j + u;
                s[u] = ssrc[beg + ((idx < d) ? idx : (d - 1))];
            }
#pragma unroll
            for (int u = 0; u < 8; u++) v[u] = Hv[(size_t)s[u] * 64 + lane];
#pragma unroll
            for (int u = 0; u < 8; u++) {
                if (j + u < d) { acc.x += v[u].x; acc.y += v[u].y; }
            }
        }
        float2 b = ((const float2*)bias)[lane];
        float2 o = make_float2(fmaf(di, acc.x, b.x), fmaf(di, acc.y, b.y));
        if (RELU) { o.x = fmaxf(o.x, 0.f); o.y = fmaxf(o.y, 0.f); }
        ((float2*)out)[(size_t)node * 64 + lane] = o;
    } else {
        float acc = H[(size_t)node * 64 + lane];            // self-loop term
        for (int j = 0; j < d; j += 8) {
            int s[8]; float v[8];
#pragma unroll
            for (int u = 0; u < 8; u++) {
                int idx = j + u;
                s[u] = ssrc[beg + ((idx < d) ? idx : (d - 1))];
            }
#pragma unroll
            for (int u = 0; u < 8; u++) v[u] = H[(size_t)s[u] * 64 + lane];
#pragma unroll
            for (int u = 0; u < 8; u++) {
                if (j + u < d) acc += v[u];
            }
        }
        float o = fmaf(di, acc, bias[lane]);
        if (RELU) o = fmaxf(o, 0.f);
        out[(size_t)node * 64 + lane] = o;
    }
}

// ---------------- launch ----------------

extern "C" void kernel_launch(void* const* d_in, const int* in_sizes, int n_in,
                              void* d_out, int out_size, void* d_ws, size_t ws_size,
                              hipStream_t stream) {
    const float* x  = (const float*)d_in[0];   // [N,128]
    const int*   ei = (const int*)d_in[1];     // [2,E]
    const float* W1 = (const float*)d_in[2];   // [128,128]
    const float* b1 = (const float*)d_in[3];   // [128]
    const float* W2 = (const float*)d_in[4];   // [128,64]
    const float* b2 = (const float*)d_in[5];   // [64]
    float* out = (float*)d_out;                // [N,64]

    const int* src = ei;
    const int* dst = ei + N_EDGES;

    char* p = (char*)d_ws;
    size_t off = 0;
    auto alloc = [&](size_t bytes) { void* q = p + off; off += (bytes + 255) & ~(size_t)255; return q; };
    float*  dinv    = (float*) alloc(N_NODES * 4);
    int*    deg     = (int*)   alloc(N_NODES * 4);
    int*    row_off = (int*)   alloc(N_NODES * 4);
    int*    cursor  = (int*)   alloc(N_NODES * 4);
    int*    parts   = (int*)   alloc(64 * 4);
    int*    ssrc    = (int*)   alloc(N_EDGES * 4);
    __bf16* w1hi    = (__bf16*)alloc(128 * 128 * 2);
    __bf16* w1lo    = (__bf16*)alloc(128 * 128 * 2);
    __bf16* w2hi    = (__bf16*)alloc(128 * 64 * 2);
    __bf16* w2lo    = (__bf16*)alloc(128 * 64 * 2);
    float*  h_buf   = (float*) alloc((size_t)N_NODES * 128 * 4);
    float*  x2      = (float*) alloc((size_t)N_NODES * 128 * 4);

    const int nb_scan = (N_NODES + 1023) / 1024;       // 49

    hipMemsetAsync(deg, 0, N_NODES * sizeof(int), stream);
    count_kernel<<<(N_EDGES + 255) / 256, 256, 0, stream>>>(dst, deg);
    scan_part_kernel<<<nb_scan, 256, 0, stream>>>(deg, parts);
    scan_blocks_kernel<<<1, 64, 0, stream>>>(parts, nb_scan);
    scan_final_kernel<<<nb_scan, 256, 0, stream>>>(deg, parts, row_off, cursor, dinv);
    fill_kernel<<<(N_EDGES + 255) / 256, 256, 0, stream>>>(src, dst, cursor, ssrc);

    wprep_kernel<128><<<8, 256, 0, stream>>>(W1, w1hi, w1lo);   // 2048 frags-lanes
    wprep_kernel<64> <<<4, 256, 0, stream>>>(W2, w2hi, w2lo);   // 1024

    // layer 1
    gemm_mfma_kernel<128><<<(N_NODES + 63) / 64, 256, 0, stream>>>(x, w1hi, w1lo, dinv, h_buf);
    aggregate_kernel<128, true><<<(N_NODES * 64 + 255) / 256, 256, 0, stream>>>(
        h_buf, row_off, deg, ssrc, dinv, b1, x2);

    // layer 2
    gemm_mfma_kernel<64><<<(N_NODES + 63) / 64, 256, 0, stream>>>(x2, w2hi, w2lo, dinv, h_buf);
    aggregate_kernel<64, false><<<(N_NODES * 64 + 255) / 256, 256, 0, stream>>>(
        h_buf, row_off, deg, ssrc, dinv, b2, out);
}